// Round 7
// baseline (492.549 us; speedup 1.0000x reference)
//
#include <hip/hip_runtime.h>
#include <hip/hip_bf16.h>

typedef __attribute__((ext_vector_type(8))) short short8;
typedef __attribute__((ext_vector_type(16))) float f32x16;

union U8 { short8 s; unsigned int u[4]; };

static __device__ __forceinline__ unsigned short f2bf(float f) {
  unsigned int u = __float_as_uint(f);
  u += 0x7fffu + ((u >> 16) & 1u);
  return (unsigned short)(u >> 16);
}
static __device__ __forceinline__ float bf2f(unsigned short h) {
  return __uint_as_float(((unsigned int)h) << 16);
}
// v_cvt_pk_bf16_f32: low half = bf16(lo), high half = bf16(hi), RNE
static __device__ __forceinline__ unsigned int cvtpk(float lo, float hi) {
  unsigned int r;
  asm("v_cvt_pk_bf16_f32 %0, %1, %2" : "=v"(r) : "v"(lo), "v"(hi));
  return r;
}
static __device__ __forceinline__ unsigned int pkrelu(float a, float b) {
  return cvtpk(fmaxf(a, 0.0f), fmaxf(b, 0.0f));
}
static __device__ __forceinline__ f32x16 MFMA(short8 a, short8 b, f32x16 c) {
  return __builtin_amdgcn_mfma_f32_32x32x16_bf16(a, b, c, 0, 0, 0);
}

// ---------------------------------------------------------------------------
// prep_all (single dispatch): zero xmax, build bf16 weight images, build
// starts[] (starts[s] = first i with batch[i] >= s; batch sorted).
// ---------------------------------------------------------------------------
__global__ void prep_all(const float* __restrict__ w1, const float* __restrict__ w2,
                         const float* __restrict__ w3, const int* __restrict__ batch,
                         unsigned short* __restrict__ w1p, uint4* __restrict__ wimg,
                         float* __restrict__ xmax, int* __restrict__ starts,
                         int useP, int N, int B) {
  const int i = blockIdx.x * 256 + threadIdx.x;
  if (i < B * 256) xmax[i] = 0.0f;
  if (useP) {
    if (i == 0) {
      const int b0 = batch[0];
      for (int s = 0; s <= b0; ++s) starts[s] = 0;
      const int bl = batch[N - 1];
      for (int s = bl + 1; s <= B; ++s) starts[s] = N;
    } else if (i < N) {
      const int a = batch[i - 1], b = batch[i];
      for (int s = a + 1; s <= b; ++s) starts[s] = i;
    }
  }
  if (i < 512) {
    { int c = i >> 4, k = i & 15; w1p[i] = (k < 6) ? f2bf(w1[c * 6 + k]) : (unsigned short)0; }
    const int l31 = i & 31, rest = i >> 5;
    const int g = rest & 1, n = (rest >> 1) & 1, t2 = rest >> 2;
    const float* src = w2 + (l31 + 32 * t2) * 32 + n * 16 + 8 * g;
    uint4 v;
    v.x = (unsigned)f2bf(src[0]) | ((unsigned)f2bf(src[1]) << 16);
    v.y = (unsigned)f2bf(src[2]) | ((unsigned)f2bf(src[3]) << 16);
    v.z = (unsigned)f2bf(src[4]) | ((unsigned)f2bf(src[5]) << 16);
    v.w = (unsigned)f2bf(src[6]) | ((unsigned)f2bf(src[7]) << 16);
    wimg[i] = v;
  }
  if (i < 4096) {
    const int l31 = i & 31, rest = i >> 5;
    const int g = rest & 1, k0 = (rest >> 1) & 7, t = rest >> 4;
    const float* src = w3 + (l31 + 32 * t) * 128 + k0 * 16 + 8 * g;
    uint4 v;
    v.x = (unsigned)f2bf(src[0]) | ((unsigned)f2bf(src[1]) << 16);
    v.y = (unsigned)f2bf(src[2]) | ((unsigned)f2bf(src[3]) << 16);
    v.z = (unsigned)f2bf(src[4]) | ((unsigned)f2bf(src[5]) << 16);
    v.w = (unsigned)f2bf(src[6]) | ((unsigned)f2bf(src[7]) << 16);
    wimg[512 + i] = v;
  }
}

// ---------------------------------------------------------------------------
// Fused per-point MLP (6->32->128->256, bf16 MFMA) + segment-max.
// 8 waves/block; w2+w3 staged once per block in LDS (72KB, fragment-major).
// Activations stay in registers (cvt_pk + shfl_xor(32) transpose).
// Segment-max output, per wave (useP path):
//  - wave's FIRST segment  -> partial row 2*wid   (shared with prev wave)
//  - wave's LAST segment   -> partial row 2*wid+1 (shared with next wave)
//  - interior segments     -> wave owns ALL their points: plain f32 store
//  - >2 segs in a 32-pt subtile (restAny) -> rare atomicMax fallback
// Head gathers base xmax + the <=2 rows of each intersecting wave.
// ---------------------------------------------------------------------------
__global__ __launch_bounds__(512, 4) void mlp_segmax_mfma(
    const float* __restrict__ points, const float* __restrict__ color,
    const int* __restrict__ batch,
    const unsigned short* __restrict__ w1p, const uint4* __restrict__ wimg,
    const float* __restrict__ b1, const float* __restrict__ b2, const float* __restrict__ b3,
    float* __restrict__ xmax, int* __restrict__ Pid, unsigned short* __restrict__ Pval,
    int useP, int N)
{
  __shared__ __align__(16) uint4 smem[4608];   // 8KB w2 image + 64KB w3 image
  const int tid  = threadIdx.x;
  const int wv   = tid >> 6;
  const int lane = tid & 63;
  const int g    = lane >> 5;
  const int l31  = lane & 31;

  for (int i = tid; i < 4608; i += 512) smem[i] = wimg[i];
  __syncthreads();
  const char* w2c = (const char*)smem;
  const char* w3c = (const char*)(smem + 512);

  const short8 a1 = *reinterpret_cast<const short8*>(w1p + l31 * 16 + 8 * g);
  float b3v[8];
#pragma unroll
  for (int t = 0; t < 8; ++t) b3v[t] = b3[32 * t + l31];

  const int wid = blockIdx.x * 8 + wv;
  const long long wbase = (long long)wid * 256;
  const int rowbase = 2 * wid;
  bool used0 = false, used1 = false;
  int firstSeg = -1, lastSeg = -1;
  if (wbase < (long long)N) {
    firstSeg = batch[(int)wbase];
    lastSeg  = batch[min((int)wbase + 255, N - 1)];
  }
  int cur = -1;
  float rmax[8];
#pragma unroll
  for (int t = 0; t < 8; ++t) rmax[t] = -INFINITY;

  auto flushP = [&]() {
    if (cur < 0) return;
    if (useP) {
      int row = -1;
      if (cur == firstSeg) { row = rowbase; used0 = true; }
      else if (cur == lastSeg) { row = rowbase + 1; used1 = true; }
      if (row >= 0) {
        if (lane == 0) Pid[row] = cur;
#pragma unroll
        for (int t = 0; t < 8; ++t) {
          float v = fmaxf(rmax[t], __shfl_xor(rmax[t], 32));
          if ((t >> 2) == g) Pval[row * 256 + 32 * t + l31] = f2bf(v);
        }
      } else {
        // interior segment: exclusively owned by this wave -> plain store
#pragma unroll
        for (int t = 0; t < 8; ++t) {
          float v = fmaxf(rmax[t], __shfl_xor(rmax[t], 32));
          if (lane < 32) xmax[(long long)cur * 256 + 32 * t + lane] = v;
        }
      }
    } else {
#pragma unroll
      for (int t = 0; t < 8; ++t) {
        float v = fmaxf(rmax[t], __shfl_xor(rmax[t], 32));
        if (lane < 32 && v > 0.0f)
          atomicMax((int*)xmax + (long long)cur * 256 + 32 * t + lane, __float_as_int(v));
      }
    }
  };

  // ---- input prefetch for subtile 0 ----
  float n0 = 0, n1 = 0, n2 = 0, n3 = 0, n4 = 0, n5 = 0;
  int nseg = -2 - lane;
  if (wbase < (long long)N) {
    const int p = (int)wbase + l31;
    n0 = points[p * 3 + 0]; n1 = points[p * 3 + 1]; n2 = points[p * 3 + 2];
    n3 = color[p * 3 + 0];  n4 = color[p * 3 + 1];  n5 = color[p * 3 + 2];
    nseg = batch[p];
  }

  for (int it = 0; it < 8; ++it) {
    const long long base = wbase + (long long)it * 32;
    if (base >= (long long)N) break;   // N % 32 == 0 for this problem

    const float c0 = n0, c1 = n1, c2 = n2, c3 = n3, c4 = n4, c5 = n5;
    const int segv = nseg;
    if (base + 32 < (long long)N && it < 7) {
      const int p = (int)base + 32 + l31;
      n0 = points[p * 3 + 0]; n1 = points[p * 3 + 1]; n2 = points[p * 3 + 2];
      n3 = color[p * 3 + 0];  n4 = color[p * 3 + 1];  n5 = color[p * 3 + 2];
      nseg = batch[p];
    }

    // opaque per-iteration handles: keep bias loads + LDS reads inside the loop
    unsigned long long b1a = (unsigned long long)b1; asm volatile("" : "+s"(b1a));
    unsigned long long b2a = (unsigned long long)b2; asm volatile("" : "+s"(b2a));
    const float* b1l = (const float*)b1a;
    const float* b2l = (const float*)b2a;
    int z = 0; asm volatile("" : "+v"(z));   // opaque 0 for LDS offsets

    // ---------------- layer 1 (6->32): D[ch][pt] ----------------
    const unsigned int zm = (g == 0) ? 0xffffffffu : 0u;  // g=1 lanes = K-pad
    U8 bin;
    bin.u[0] = cvtpk(c0, c1) & zm;
    bin.u[1] = cvtpk(c2, c3) & zm;
    bin.u[2] = cvtpk(c4, c5) & zm;
    bin.u[3] = 0;
    f32x16 ci;
#pragma unroll
    for (int q2 = 0; q2 < 4; ++q2) {
      const float4 bv = *reinterpret_cast<const float4*>(b1l + 8 * q2 + 4 * g);
      ci[4 * q2 + 0] = bv.x; ci[4 * q2 + 1] = bv.y; ci[4 * q2 + 2] = bv.z; ci[4 * q2 + 3] = bv.w;
    }
    f32x16 d1 = MFMA(a1, bin.s, ci);

    unsigned int W1[4][2];
#pragma unroll
    for (int q2 = 0; q2 < 4; ++q2) {
      W1[q2][0] = pkrelu(d1[4 * q2 + 0], d1[4 * q2 + 1]);
      W1[q2][1] = pkrelu(d1[4 * q2 + 2], d1[4 * q2 + 3]);
    }
    U8 h1f[2];
#pragma unroll
    for (int n = 0; n < 2; ++n) {
      unsigned int r0 = __shfl_xor(W1[2 * n + 1 - g][0], 32);
      unsigned int r1 = __shfl_xor(W1[2 * n + 1 - g][1], 32);
      h1f[n].u[0] = (g == 0) ? W1[2 * n + g][0] : r0;
      h1f[n].u[1] = (g == 0) ? W1[2 * n + g][1] : r1;
      h1f[n].u[2] = (g == 1) ? W1[2 * n + g][0] : r0;
      h1f[n].u[3] = (g == 1) ? W1[2 * n + g][1] : r1;
    }

    // ---------------- layer 2 (32->128): D[ch][pt] per 32-ch tile ----------------
    unsigned int own2[4][2][2], rc2[4][2][2];
#pragma unroll
    for (int t2 = 0; t2 < 4; ++t2) {
      f32x16 cc;
#pragma unroll
      for (int q2 = 0; q2 < 4; ++q2) {
        const float4 bv = *reinterpret_cast<const float4*>(b2l + 32 * t2 + 8 * q2 + 4 * g);
        cc[4 * q2 + 0] = bv.x; cc[4 * q2 + 1] = bv.y; cc[4 * q2 + 2] = bv.z; cc[4 * q2 + 3] = bv.w;
      }
      const short8 a20 = *reinterpret_cast<const short8*>(
          w2c + ((((t2 * 2 + 0) * 2 + g) * 32 + l31) << 4) + z);
      const short8 a21 = *reinterpret_cast<const short8*>(
          w2c + ((((t2 * 2 + 1) * 2 + g) * 32 + l31) << 4) + z);
      f32x16 d2 = MFMA(a20, h1f[0].s, cc);
      d2 = MFMA(a21, h1f[1].s, d2);
      unsigned int Wt[4][2];
#pragma unroll
      for (int q2 = 0; q2 < 4; ++q2) {
        Wt[q2][0] = pkrelu(d2[4 * q2 + 0], d2[4 * q2 + 1]);
        Wt[q2][1] = pkrelu(d2[4 * q2 + 2], d2[4 * q2 + 3]);
      }
#pragma unroll
      for (int m = 0; m < 2; ++m) {
        own2[t2][m][0] = Wt[2 * m + g][0];
        own2[t2][m][1] = Wt[2 * m + g][1];
        rc2[t2][m][0] = __shfl_xor(Wt[2 * m + 1 - g][0], 32);
        rc2[t2][m][1] = __shfl_xor(Wt[2 * m + 1 - g][1], 32);
      }
    }
    U8 a3[8];
#pragma unroll
    for (int k0 = 0; k0 < 8; ++k0) {
      const int t2 = k0 >> 1, m = k0 & 1;
      a3[k0].u[0] = (g == 0) ? own2[t2][m][0] : rc2[t2][m][0];
      a3[k0].u[1] = (g == 0) ? own2[t2][m][1] : rc2[t2][m][1];
      a3[k0].u[2] = (g == 1) ? own2[t2][m][0] : rc2[t2][m][0];
      a3[k0].u[3] = (g == 1) ? own2[t2][m][1] : rc2[t2][m][1];
    }

    // ---------------- segment bookkeeping ----------------
    const int segA = __builtin_amdgcn_readfirstlane(segv);
    const int segD = __shfl(segv, 31);
    const bool caseU = (segA == segD);
    if (segA != cur) {
      flushP();
#pragma unroll
      for (int t = 0; t < 8; ++t) rmax[t] = -INFINITY;
      cur = segA;
    }
    unsigned int bA = 0, bD = 0;
    bool restAny = false;
    int rowA = -1; bool dirA = false;
    if (!caseU) {
      bA = (unsigned int)__ballot(segv == segA);
      bD = (unsigned int)__ballot(segv == segD);
      restAny = ((bA | bD) != 0xffffffffu);
      if (useP) {
        if (segA == firstSeg) { rowA = rowbase; used0 = true; }
        else if (segA == lastSeg) { rowA = rowbase + 1; used1 = true; }
        else dirA = true;
        if (rowA >= 0 && lane == 0) Pid[rowA] = segA;
      }
    }

    // ---------------- layer 3 (128->256): D[pt][ch], col=channel ----------------
#pragma unroll
    for (int t = 0; t < 8; ++t) {
      f32x16 acc;
#pragma unroll
      for (int r2 = 0; r2 < 16; ++r2) acc[r2] = b3v[t];
#pragma unroll
      for (int k0 = 0; k0 < 8; ++k0) {
        const short8 bf = *reinterpret_cast<const short8*>(
            w3c + ((((t * 8 + k0) * 2 + g) * 32 + l31) << 4) + z);
        acc = MFMA(a3[k0].s, bf, acc);
      }
      if (caseU) {
        float m = acc[0];
#pragma unroll
        for (int r2 = 1; r2 < 16; ++r2) m = fmaxf(m, acc[r2]);
        rmax[t] = fmaxf(rmax[t], m);
      } else {
        float ma = -INFINITY, md = -INFINITY;
#pragma unroll
        for (int r2 = 0; r2 < 16; ++r2) {
          const int idx = (r2 & 3) + 8 * (r2 >> 2) + 4 * g;
          const unsigned int bit = 1u << idx;
          const float v = acc[r2];
          ma = fmaxf(ma, (bA & bit) ? v : -INFINITY);
          md = fmaxf(md, (bD & bit) ? v : -INFINITY);
        }
        if (restAny) {   // >2 segments inside one 32-pt subtile: rare slow path
#pragma unroll
          for (int r2 = 0; r2 < 16; ++r2) {
            const int idx = (r2 & 3) + 8 * (r2 >> 2) + 4 * g;
            const unsigned int bit = 1u << idx;
            if (!((bA | bD) & bit)) {
              const int sid = __shfl(segv, idx);
              const float v = acc[r2];
              if (sid >= 0 && v > 0.0f)
                atomicMax((int*)xmax + (long long)sid * 256 + 32 * t + l31, __float_as_int(v));
            }
          }
        }
        // close segA for this channel group
        float va = fmaxf(rmax[t], ma);
        va = fmaxf(va, __shfl_xor(va, 32));
        if (rowA >= 0) {
          if ((t >> 2) == g) Pval[rowA * 256 + 32 * t + l31] = f2bf(va);
        } else if (dirA) {
          if (lane < 32) xmax[(long long)segA * 256 + 32 * t + lane] = va;
        } else if (lane < 32 && va > 0.0f) {
          atomicMax((int*)xmax + (long long)segA * 256 + 32 * t + lane, __float_as_int(va));
        }
        rmax[t] = md;    // start accumulating segD
      }
    }
    if (!caseU) cur = segD;
  }
  flushP();
  if (useP && lane == 0) {
    if (!used0) Pid[rowbase] = -1;
    if (!used1) Pid[rowbase + 1] = -1;
  }
}

// ---------------------------------------------------------------------------
// FC head  [B,256] -> 128 -> 64 -> 75, + coef scale/shift.
// Stage loop gathers base xmax + the 2 partial rows of each intersecting wave.
// ---------------------------------------------------------------------------
__global__ __launch_bounds__(256) void head_kernel(
    const float* __restrict__ xmax,
    const int* __restrict__ starts, const int* __restrict__ Pid,
    const unsigned short* __restrict__ Pval, int useP,
    const float* __restrict__ fw1, const float* __restrict__ fb1,
    const float* __restrict__ fw2, const float* __restrict__ fb2,
    const float* __restrict__ fw3, const float* __restrict__ fb3,
    const float* __restrict__ cmean, const float* __restrict__ cstd,
    float* __restrict__ out, int B)
{
  __shared__ __align__(16) float xm[16][260];
  __shared__ __align__(16) float h1b[16][132];
  __shared__ __align__(16) float h2b[16][68];

  const int t = threadIdx.x;
  const int bbase = blockIdx.x * 16;

  // stage 16 rows of xmax, gathering the per-wave partial maxima
  for (int i = t; i < 16 * 256; i += 256) {
    const int bi = i >> 8, k = i & 255;   // all threads share bi per iteration
    const int s = min(bbase + bi, B - 1);
    float acc = xmax[(long long)s * 256 + k];   // direct stores + rare atomics + 0
    if (useP) {
      const int i0 = starts[s], i1 = starts[s + 1];
      if (i1 > i0) {
        const int w0 = i0 >> 8, w1 = (i1 - 1) >> 8;
        for (int w = w0; w <= w1; ++w) {
#pragma unroll
          for (int j = 0; j < 2; ++j) {
            const int row = 2 * w + j;
            if (Pid[row] == s) acc = fmaxf(acc, bf2f(Pval[row * 256 + k]));
          }
        }
      }
    }
    xm[bi][k] = fmaxf(acc, 0.0f);   // clamp-at-0 (scatter amax onto zeros)
  }
  __syncthreads();

  {
    const int bi = t >> 4, oi = t & 15;
    float acc[8];
#pragma unroll
    for (int u = 0; u < 8; ++u) acc[u] = fb1[oi * 8 + u];
    for (int k = 0; k < 256; k += 4) {
      const float4 xv = *reinterpret_cast<const float4*>(&xm[bi][k]);
#pragma unroll
      for (int u = 0; u < 8; ++u) {
        const float4 wv = *reinterpret_cast<const float4*>(fw1 + (oi * 8 + u) * 256 + k);
        acc[u] = fmaf(xv.x, wv.x, acc[u]);
        acc[u] = fmaf(xv.y, wv.y, acc[u]);
        acc[u] = fmaf(xv.z, wv.z, acc[u]);
        acc[u] = fmaf(xv.w, wv.w, acc[u]);
      }
    }
#pragma unroll
    for (int u = 0; u < 8; ++u) h1b[bi][oi * 8 + u] = fmaxf(acc[u], 0.0f);
  }
  __syncthreads();

  {
    const int bi = t >> 4, oi = t & 15;
    float acc[4];
#pragma unroll
    for (int u = 0; u < 4; ++u) acc[u] = fb2[oi * 4 + u];
    for (int k = 0; k < 128; k += 4) {
      const float4 xv = *reinterpret_cast<const float4*>(&h1b[bi][k]);
#pragma unroll
      for (int u = 0; u < 4; ++u) {
        const float4 wv = *reinterpret_cast<const float4*>(fw2 + (oi * 4 + u) * 128 + k);
        acc[u] = fmaf(xv.x, wv.x, acc[u]);
        acc[u] = fmaf(xv.y, wv.y, acc[u]);
        acc[u] = fmaf(xv.z, wv.z, acc[u]);
        acc[u] = fmaf(xv.w, wv.w, acc[u]);
      }
    }
#pragma unroll
    for (int u = 0; u < 4; ++u) h2b[bi][oi * 4 + u] = fmaxf(acc[u], 0.0f);
  }
  __syncthreads();

  for (int i = t; i < 16 * 75; i += 256) {
    const int bi = i / 75, o = i - bi * 75;
    float a = fb3[o];
    for (int k = 0; k < 64; k += 4) {
      const float4 xv = *reinterpret_cast<const float4*>(&h2b[bi][k]);
      const float4 wv = *reinterpret_cast<const float4*>(fw3 + o * 64 + k);
      a = fmaf(xv.x, wv.x, a);
      a = fmaf(xv.y, wv.y, a);
      a = fmaf(xv.z, wv.z, a);
      a = fmaf(xv.w, wv.w, a);
    }
    const int b = bbase + bi;
    if (b < B) out[(long long)b * 75 + o] = fmaf(a, cstd[o], cmean[o]);
  }
}

extern "C" void kernel_launch(void* const* d_in, const int* in_sizes, int n_in,
                              void* d_out, int out_size, void* d_ws, size_t ws_size,
                              hipStream_t stream) {
  const float* points = (const float*)d_in[0];
  const float* color  = (const float*)d_in[1];
  const int*   batch  = (const int*)d_in[2];
  const float* w1  = (const float*)d_in[3];
  const float* b1  = (const float*)d_in[4];
  const float* w2  = (const float*)d_in[5];
  const float* b2  = (const float*)d_in[6];
  const float* w3  = (const float*)d_in[7];
  const float* b3  = (const float*)d_in[8];
  const float* fw1 = (const float*)d_in[9];
  const float* fb1 = (const float*)d_in[10];
  const float* fw2 = (const float*)d_in[11];
  const float* fb2 = (const float*)d_in[12];
  const float* fw3 = (const float*)d_in[13];
  const float* fb3 = (const float*)d_in[14];
  const float* cmean = (const float*)d_in[15];
  const float* cstd  = (const float*)d_in[16];
  float* out = (float*)d_out;

  const int N = in_sizes[2];
  const int B = out_size / 75;

  const int nWaves  = (N + 255) / 256;
  const int nBlocks = (nWaves + 7) / 8;
  const int NROWS   = 2 * nBlocks * 8;

  // workspace layout (total ~7.94 MiB for N=1e6, B=4096)
  char* ws = (char*)d_ws;
  size_t off = 0;
  float* xmax = (float*)(ws + off);            off += (size_t)B * 256 * 4;
  unsigned short* w1p = (unsigned short*)(ws + off); off += 1024;
  uint4* wimg = (uint4*)(ws + off);            off += 4608 * 16;
  int* starts = (int*)(ws + off);              off += ((size_t)(B + 1) * 4 + 15) & ~(size_t)15;
  int* Pid = (int*)(ws + off);                 off += ((size_t)NROWS * 4 + 15) & ~(size_t)15;
  unsigned short* Pval = (unsigned short*)(ws + off);
  const size_t needed = off + (size_t)NROWS * 512;
  const int useP = (ws_size >= needed) ? 1 : 0;

  const int M = (N > B * 256) ? N : B * 256;
  prep_all<<<(M + 255) / 256, 256, 0, stream>>>(w1, w2, w3, batch, w1p, wimg,
                                                xmax, starts, useP, N, B);

  mlp_segmax_mfma<<<nBlocks, 512, 0, stream>>>(points, color, batch,
                                               w1p, wimg, b1, b2, b3,
                                               xmax, Pid, Pval, useP, N);

  head_kernel<<<(B + 15) / 16, 256, 0, stream>>>(xmax, starts, Pid, Pval, useP,
                                                 fw1, fb1, fw2, fb2, fw3, fb3,
                                                 cmean, cstd, out, B);
}

// Round 8
// 425.878 us; speedup vs baseline: 1.1565x; 1.1565x over previous
//
#include <hip/hip_runtime.h>
#include <hip/hip_bf16.h>

typedef __attribute__((ext_vector_type(8))) short short8;
typedef __attribute__((ext_vector_type(16))) float f32x16;

union U8 { short8 s; unsigned int u[4]; };

static __device__ __forceinline__ unsigned short f2bf(float f) {
  unsigned int u = __float_as_uint(f);
  u += 0x7fffu + ((u >> 16) & 1u);
  return (unsigned short)(u >> 16);
}
// v_cvt_pk_bf16_f32: low half = bf16(lo), high half = bf16(hi), RNE
static __device__ __forceinline__ unsigned int cvtpk(float lo, float hi) {
  unsigned int r;
  asm("v_cvt_pk_bf16_f32 %0, %1, %2" : "=v"(r) : "v"(lo), "v"(hi));
  return r;
}
static __device__ __forceinline__ unsigned int pkrelu(float a, float b) {
  return cvtpk(fmaxf(a, 0.0f), fmaxf(b, 0.0f));
}
static __device__ __forceinline__ f32x16 MFMA(short8 a, short8 b, f32x16 c) {
  return __builtin_amdgcn_mfma_f32_32x32x16_bf16(a, b, c, 0, 0, 0);
}

// ---------------------------------------------------------------------------
// prep: build bf16 weight images in workspace (fragment-major, conflict-free)
// ---------------------------------------------------------------------------
__global__ void prep_weights(const float* __restrict__ w1, const float* __restrict__ w2,
                             const float* __restrict__ w3,
                             unsigned short* __restrict__ w1p, uint4* __restrict__ wimg) {
  const int i = blockIdx.x * 256 + threadIdx.x;   // 4096 threads
  if (i < 512) {
    { int c = i >> 4, k = i & 15; w1p[i] = (k < 6) ? f2bf(w1[c * 6 + k]) : (unsigned short)0; }
    const int l31 = i & 31, rest = i >> 5;
    const int g = rest & 1, n = (rest >> 1) & 1, t2 = rest >> 2;
    const float* src = w2 + (l31 + 32 * t2) * 32 + n * 16 + 8 * g;
    uint4 v;
    v.x = (unsigned)f2bf(src[0]) | ((unsigned)f2bf(src[1]) << 16);
    v.y = (unsigned)f2bf(src[2]) | ((unsigned)f2bf(src[3]) << 16);
    v.z = (unsigned)f2bf(src[4]) | ((unsigned)f2bf(src[5]) << 16);
    v.w = (unsigned)f2bf(src[6]) | ((unsigned)f2bf(src[7]) << 16);
    wimg[i] = v;
  }
  if (i < 4096) {
    const int l31 = i & 31, rest = i >> 5;
    const int g = rest & 1, k0 = (rest >> 1) & 7, t = rest >> 4;
    const float* src = w3 + (l31 + 32 * t) * 128 + k0 * 16 + 8 * g;
    uint4 v;
    v.x = (unsigned)f2bf(src[0]) | ((unsigned)f2bf(src[1]) << 16);
    v.y = (unsigned)f2bf(src[2]) | ((unsigned)f2bf(src[3]) << 16);
    v.z = (unsigned)f2bf(src[4]) | ((unsigned)f2bf(src[5]) << 16);
    v.w = (unsigned)f2bf(src[6]) | ((unsigned)f2bf(src[7]) << 16);
    wimg[512 + i] = v;
  }
}

// ---------------------------------------------------------------------------
// Fused per-point MLP (6->32->128->256, bf16 MFMA) + segment-max.
// 8 waves/block; w2+w3 staged once per block in LDS (72KB, fragment-major).
// Activations stay in registers (cvt_pk + shfl_xor(32) transpose).
// NEW (R8): NO mid-loop atomics. vmcnt retires IN ORDER, so a mid-loop
// device-scope atomicMax (fabric RMW, us-scale) blocks the vmcnt decrement
// of every later input/bias load -> each segment transition stalled the wave
// for the full atomic round trip. Completed segments' maxima are parked in
// registers (pA/pB, 2 slots) and ALL atomics issue after the last subtile,
// when nothing can wait on them. Mid-loop atomics remain only for
// statistically-absent cases (>=4 segs/wave, >=3 segs in a 32-pt subtile).
// ---------------------------------------------------------------------------
__global__ __launch_bounds__(512, 4) void mlp_segmax_mfma(
    const float* __restrict__ points, const float* __restrict__ color,
    const int* __restrict__ batch,
    const unsigned short* __restrict__ w1p, const uint4* __restrict__ wimg,
    const float* __restrict__ b1, const float* __restrict__ b2, const float* __restrict__ b3,
    float* __restrict__ xmax, int N)
{
  __shared__ __align__(16) uint4 smem[4608];   // 8KB w2 image + 64KB w3 image
  const int tid  = threadIdx.x;
  const int wv   = tid >> 6;
  const int lane = tid & 63;
  const int g    = lane >> 5;
  const int l31  = lane & 31;

  for (int i = tid; i < 4608; i += 512) smem[i] = wimg[i];
  __syncthreads();
  const char* w2c = (const char*)smem;
  const char* w3c = (const char*)(smem + 512);

  const short8 a1 = *reinterpret_cast<const short8*>(w1p + l31 * 16 + 8 * g);
  float b3v[8];
#pragma unroll
  for (int t = 0; t < 8; ++t) b3v[t] = b3[32 * t + l31];

  const int wid = blockIdx.x * 8 + wv;
  const long long wbase = (long long)wid * 256;

  int cur = -1;
  float rmax[8];
#pragma unroll
  for (int t = 0; t < 8; ++t) rmax[t] = -INFINITY;

  // pending completed segments (registers) — flushed at kernel end
  float pA[8], pB[8];
  int idA = -1, idB = -1, nsv = 0;

  auto atomicFlush = [&](int sid, const float* vals) {
#pragma unroll
    for (int t = 0; t < 8; ++t) {
      float v = fmaxf(vals[t], __shfl_xor(vals[t], 32));
      if (lane < 32 && v > 0.0f)
        atomicMax((int*)xmax + (long long)sid * 256 + 32 * t + lane, __float_as_int(v));
    }
  };
  auto savePend = [&](int sid, const float* vals) {
    if (nsv == 2) {                 // rare overflow (>=4 segs in one wave)
      atomicFlush(idA, pA);
#pragma unroll
      for (int t = 0; t < 8; ++t) pA[t] = pB[t];
      idA = idB; nsv = 1;
    }
    if (nsv == 0) {
      idA = sid;
#pragma unroll
      for (int t = 0; t < 8; ++t) pA[t] = vals[t];
    } else {
      idB = sid;
#pragma unroll
      for (int t = 0; t < 8; ++t) pB[t] = vals[t];
    }
    ++nsv;
  };

  // ---- input prefetch for subtile 0 ----
  float n0 = 0, n1 = 0, n2 = 0, n3 = 0, n4 = 0, n5 = 0;
  int nseg = -2 - lane;
  if (wbase < (long long)N) {
    const int p = (int)wbase + l31;
    n0 = points[p * 3 + 0]; n1 = points[p * 3 + 1]; n2 = points[p * 3 + 2];
    n3 = color[p * 3 + 0];  n4 = color[p * 3 + 1];  n5 = color[p * 3 + 2];
    nseg = batch[p];
  }

  for (int it = 0; it < 8; ++it) {
    const long long base = wbase + (long long)it * 32;
    if (base >= (long long)N) break;   // N % 32 == 0 for this problem

    const float c0 = n0, c1 = n1, c2 = n2, c3 = n3, c4 = n4, c5 = n5;
    const int segv = nseg;
    if (base + 32 < (long long)N && it < 7) {
      const int p = (int)base + 32 + l31;
      n0 = points[p * 3 + 0]; n1 = points[p * 3 + 1]; n2 = points[p * 3 + 2];
      n3 = color[p * 3 + 0];  n4 = color[p * 3 + 1];  n5 = color[p * 3 + 2];
      nseg = batch[p];
    }

    // opaque per-iteration handles: keep bias loads + LDS reads inside the loop
    unsigned long long b1a = (unsigned long long)b1; asm volatile("" : "+s"(b1a));
    unsigned long long b2a = (unsigned long long)b2; asm volatile("" : "+s"(b2a));
    const float* b1l = (const float*)b1a;
    const float* b2l = (const float*)b2a;
    int z = 0; asm volatile("" : "+v"(z));   // opaque 0 for LDS offsets

    // ---------------- layer 1 (6->32): D[ch][pt] ----------------
    const unsigned int zm = (g == 0) ? 0xffffffffu : 0u;  // g=1 lanes = K-pad
    U8 bin;
    bin.u[0] = cvtpk(c0, c1) & zm;
    bin.u[1] = cvtpk(c2, c3) & zm;
    bin.u[2] = cvtpk(c4, c5) & zm;
    bin.u[3] = 0;
    f32x16 ci;
#pragma unroll
    for (int q2 = 0; q2 < 4; ++q2) {
      const float4 bv = *reinterpret_cast<const float4*>(b1l + 8 * q2 + 4 * g);
      ci[4 * q2 + 0] = bv.x; ci[4 * q2 + 1] = bv.y; ci[4 * q2 + 2] = bv.z; ci[4 * q2 + 3] = bv.w;
    }
    f32x16 d1 = MFMA(a1, bin.s, ci);

    unsigned int W1[4][2];
#pragma unroll
    for (int q2 = 0; q2 < 4; ++q2) {
      W1[q2][0] = pkrelu(d1[4 * q2 + 0], d1[4 * q2 + 1]);
      W1[q2][1] = pkrelu(d1[4 * q2 + 2], d1[4 * q2 + 3]);
    }
    U8 h1f[2];
#pragma unroll
    for (int n = 0; n < 2; ++n) {
      unsigned int r0 = __shfl_xor(W1[2 * n + 1 - g][0], 32);
      unsigned int r1 = __shfl_xor(W1[2 * n + 1 - g][1], 32);
      h1f[n].u[0] = (g == 0) ? W1[2 * n + g][0] : r0;
      h1f[n].u[1] = (g == 0) ? W1[2 * n + g][1] : r1;
      h1f[n].u[2] = (g == 1) ? W1[2 * n + g][0] : r0;
      h1f[n].u[3] = (g == 1) ? W1[2 * n + g][1] : r1;
    }

    // ---------------- layer 2 (32->128): D[ch][pt] per 32-ch tile ----------------
    unsigned int own2[4][2][2], rc2[4][2][2];
#pragma unroll
    for (int t2 = 0; t2 < 4; ++t2) {
      f32x16 cc;
#pragma unroll
      for (int q2 = 0; q2 < 4; ++q2) {
        const float4 bv = *reinterpret_cast<const float4*>(b2l + 32 * t2 + 8 * q2 + 4 * g);
        cc[4 * q2 + 0] = bv.x; cc[4 * q2 + 1] = bv.y; cc[4 * q2 + 2] = bv.z; cc[4 * q2 + 3] = bv.w;
      }
      const short8 a20 = *reinterpret_cast<const short8*>(
          w2c + ((((t2 * 2 + 0) * 2 + g) * 32 + l31) << 4) + z);
      const short8 a21 = *reinterpret_cast<const short8*>(
          w2c + ((((t2 * 2 + 1) * 2 + g) * 32 + l31) << 4) + z);
      f32x16 d2 = MFMA(a20, h1f[0].s, cc);
      d2 = MFMA(a21, h1f[1].s, d2);
      unsigned int Wt[4][2];
#pragma unroll
      for (int q2 = 0; q2 < 4; ++q2) {
        Wt[q2][0] = pkrelu(d2[4 * q2 + 0], d2[4 * q2 + 1]);
        Wt[q2][1] = pkrelu(d2[4 * q2 + 2], d2[4 * q2 + 3]);
      }
#pragma unroll
      for (int m = 0; m < 2; ++m) {
        own2[t2][m][0] = Wt[2 * m + g][0];
        own2[t2][m][1] = Wt[2 * m + g][1];
        rc2[t2][m][0] = __shfl_xor(Wt[2 * m + 1 - g][0], 32);
        rc2[t2][m][1] = __shfl_xor(Wt[2 * m + 1 - g][1], 32);
      }
    }
    U8 a3[8];
#pragma unroll
    for (int k0 = 0; k0 < 8; ++k0) {
      const int t2 = k0 >> 1, m = k0 & 1;
      a3[k0].u[0] = (g == 0) ? own2[t2][m][0] : rc2[t2][m][0];
      a3[k0].u[1] = (g == 0) ? own2[t2][m][1] : rc2[t2][m][1];
      a3[k0].u[2] = (g == 1) ? own2[t2][m][0] : rc2[t2][m][0];
      a3[k0].u[3] = (g == 1) ? own2[t2][m][1] : rc2[t2][m][1];
    }

    // ---------------- segment bookkeeping ----------------
    const int segA = __builtin_amdgcn_readfirstlane(segv);
    const int segD = __shfl(segv, 31);
    const bool caseU = (segA == segD);
    if (segA != cur) {
      if (cur >= 0) savePend(cur, rmax);   // register park, no atomics
#pragma unroll
      for (int t = 0; t < 8; ++t) rmax[t] = -INFINITY;
      cur = segA;
    }
    unsigned int bA = 0, bD = 0;
    bool restAny = false;
    if (!caseU) {
      bA = (unsigned int)__ballot(segv == segA);
      bD = (unsigned int)__ballot(segv == segD);
      restAny = ((bA | bD) != 0xffffffffu);
    }

    // ---------------- layer 3 (128->256): D[pt][ch], col=channel ----------------
    float sa[8];
#pragma unroll
    for (int t = 0; t < 8; ++t) {
      f32x16 acc;
#pragma unroll
      for (int r2 = 0; r2 < 16; ++r2) acc[r2] = b3v[t];
#pragma unroll
      for (int k0 = 0; k0 < 8; ++k0) {
        const short8 bf = *reinterpret_cast<const short8*>(
            w3c + ((((t * 8 + k0) * 2 + g) * 32 + l31) << 4) + z);
        acc = MFMA(a3[k0].s, bf, acc);
      }
      if (caseU) {
        float m = acc[0];
#pragma unroll
        for (int r2 = 1; r2 < 16; ++r2) m = fmaxf(m, acc[r2]);
        rmax[t] = fmaxf(rmax[t], m);
      } else {
        float ma = -INFINITY, md = -INFINITY;
#pragma unroll
        for (int r2 = 0; r2 < 16; ++r2) {
          const int idx = (r2 & 3) + 8 * (r2 >> 2) + 4 * g;
          const unsigned int bit = 1u << idx;
          const float v = acc[r2];
          ma = fmaxf(ma, (bA & bit) ? v : -INFINITY);
          md = fmaxf(md, (bD & bit) ? v : -INFINITY);
        }
        if (restAny) {   // >2 segments inside one 32-pt subtile: ~never
#pragma unroll
          for (int r2 = 0; r2 < 16; ++r2) {
            const int idx = (r2 & 3) + 8 * (r2 >> 2) + 4 * g;
            const unsigned int bit = 1u << idx;
            if (!((bA | bD) & bit)) {
              const int sid = __shfl(segv, idx);
              const float v = acc[r2];
              if (sid >= 0 && v > 0.0f)
                atomicMax((int*)xmax + (long long)sid * 256 + 32 * t + l31, __float_as_int(v));
            }
          }
        }
        sa[t] = fmaxf(rmax[t], ma);   // segA's final value for this t
        rmax[t] = md;                 // start accumulating segD
      }
    }
    if (!caseU) { savePend(segA, sa); cur = segD; }
  }

  // ---- end-of-kernel: all atomics issue here; nothing waits on them ----
  if (cur >= 0) savePend(cur, rmax);
  if (nsv >= 1) atomicFlush(idA, pA);
  if (nsv >= 2) atomicFlush(idB, pB);
}

// ---------------------------------------------------------------------------
// FC head  [B,256] -> 128 -> 64 -> 75, + coef scale/shift (R4 version)
// ---------------------------------------------------------------------------
__global__ __launch_bounds__(256) void head_kernel(
    const float* __restrict__ xmax,
    const float* __restrict__ fw1, const float* __restrict__ fb1,
    const float* __restrict__ fw2, const float* __restrict__ fb2,
    const float* __restrict__ fw3, const float* __restrict__ fb3,
    const float* __restrict__ cmean, const float* __restrict__ cstd,
    float* __restrict__ out, int B)
{
  __shared__ __align__(16) float xm[16][260];
  __shared__ __align__(16) float h1b[16][132];
  __shared__ __align__(16) float h2b[16][68];

  const int t = threadIdx.x;
  const int bbase = blockIdx.x * 16;

  for (int i = t; i < 16 * 256; i += 256) {
    const int bi = i >> 8, k = i & 255;
    const int bb = min(bbase + bi, B - 1);
    xm[bi][k] = xmax[(long long)bb * 256 + k];
  }
  __syncthreads();

  {
    const int bi = t >> 4, oi = t & 15;
    float acc[8];
#pragma unroll
    for (int u = 0; u < 8; ++u) acc[u] = fb1[oi * 8 + u];
    for (int k = 0; k < 256; k += 4) {
      const float4 xv = *reinterpret_cast<const float4*>(&xm[bi][k]);
#pragma unroll
      for (int u = 0; u < 8; ++u) {
        const float4 wv = *reinterpret_cast<const float4*>(fw1 + (oi * 8 + u) * 256 + k);
        acc[u] = fmaf(xv.x, wv.x, acc[u]);
        acc[u] = fmaf(xv.y, wv.y, acc[u]);
        acc[u] = fmaf(xv.z, wv.z, acc[u]);
        acc[u] = fmaf(xv.w, wv.w, acc[u]);
      }
    }
#pragma unroll
    for (int u = 0; u < 8; ++u) h1b[bi][oi * 8 + u] = fmaxf(acc[u], 0.0f);
  }
  __syncthreads();

  {
    const int bi = t >> 4, oi = t & 15;
    float acc[4];
#pragma unroll
    for (int u = 0; u < 4; ++u) acc[u] = fb2[oi * 4 + u];
    for (int k = 0; k < 128; k += 4) {
      const float4 xv = *reinterpret_cast<const float4*>(&h1b[bi][k]);
#pragma unroll
      for (int u = 0; u < 4; ++u) {
        const float4 wv = *reinterpret_cast<const float4*>(fw2 + (oi * 4 + u) * 128 + k);
        acc[u] = fmaf(xv.x, wv.x, acc[u]);
        acc[u] = fmaf(xv.y, wv.y, acc[u]);
        acc[u] = fmaf(xv.z, wv.z, acc[u]);
        acc[u] = fmaf(xv.w, wv.w, acc[u]);
      }
    }
#pragma unroll
    for (int u = 0; u < 4; ++u) h2b[bi][oi * 4 + u] = fmaxf(acc[u], 0.0f);
  }
  __syncthreads();

  for (int i = t; i < 16 * 75; i += 256) {
    const int bi = i / 75, o = i - bi * 75;
    float a = fb3[o];
    for (int k = 0; k < 64; k += 4) {
      const float4 xv = *reinterpret_cast<const float4*>(&h2b[bi][k]);
      const float4 wv = *reinterpret_cast<const float4*>(fw3 + o * 64 + k);
      a = fmaf(xv.x, wv.x, a);
      a = fmaf(xv.y, wv.y, a);
      a = fmaf(xv.z, wv.z, a);
      a = fmaf(xv.w, wv.w, a);
    }
    const int b = bbase + bi;
    if (b < B) out[(long long)b * 75 + o] = fmaf(a, cstd[o], cmean[o]);
  }
}

extern "C" void kernel_launch(void* const* d_in, const int* in_sizes, int n_in,
                              void* d_out, int out_size, void* d_ws, size_t ws_size,
                              hipStream_t stream) {
  const float* points = (const float*)d_in[0];
  const float* color  = (const float*)d_in[1];
  const int*   batch  = (const int*)d_in[2];
  const float* w1  = (const float*)d_in[3];
  const float* b1  = (const float*)d_in[4];
  const float* w2  = (const float*)d_in[5];
  const float* b2  = (const float*)d_in[6];
  const float* w3  = (const float*)d_in[7];
  const float* b3  = (const float*)d_in[8];
  const float* fw1 = (const float*)d_in[9];
  const float* fb1 = (const float*)d_in[10];
  const float* fw2 = (const float*)d_in[11];
  const float* fb2 = (const float*)d_in[12];
  const float* fw3 = (const float*)d_in[13];
  const float* fb3 = (const float*)d_in[14];
  const float* cmean = (const float*)d_in[15];
  const float* cstd  = (const float*)d_in[16];
  float* out = (float*)d_out;

  const int N = in_sizes[2];
  const int B = out_size / 75;

  float* xmax = (float*)d_ws;                                       // [B][256] f32 = 4MB
  unsigned short* w1p = (unsigned short*)((char*)d_ws + 4194304);   // 1KB
  uint4* wimg = (uint4*)((char*)d_ws + 4198400);                    // 72KB images

  hipMemsetAsync(xmax, 0, (size_t)B * 256 * sizeof(float), stream);
  prep_weights<<<16, 256, 0, stream>>>(w1, w2, w3, w1p, wimg);

  const int nBlocks = (N + 2047) / 2048;   // 8 waves x 256 pts per block
  mlp_segmax_mfma<<<nBlocks, 512, 0, stream>>>(points, color, batch,
                                               w1p, wimg, b1, b2, b3, xmax, N);

  head_kernel<<<(B + 15) / 16, 256, 0, stream>>>(xmax, fw1, fb1, fw2, fb2, fw3, fb3,
                                                 cmean, cstd, out, B);
}

// Round 10
// 396.963 us; speedup vs baseline: 1.2408x; 1.0728x over previous
//
#include <hip/hip_runtime.h>
#include <hip/hip_bf16.h>

typedef __attribute__((ext_vector_type(8))) short short8;
typedef __attribute__((ext_vector_type(16))) float f32x16;

union U8 { short8 s; unsigned int u[4]; };

static __device__ __forceinline__ unsigned short f2bf(float f) {
  unsigned int u = __float_as_uint(f);
  u += 0x7fffu + ((u >> 16) & 1u);
  return (unsigned short)(u >> 16);
}
// v_cvt_pk_bf16_f32: low half = bf16(lo), high half = bf16(hi), RNE
static __device__ __forceinline__ unsigned int cvtpk(float lo, float hi) {
  unsigned int r;
  asm("v_cvt_pk_bf16_f32 %0, %1, %2" : "=v"(r) : "v"(lo), "v"(hi));
  return r;
}
static __device__ __forceinline__ unsigned int pkrelu(float a, float b) {
  return cvtpk(fmaxf(a, 0.0f), fmaxf(b, 0.0f));
}
static __device__ __forceinline__ f32x16 MFMA(short8 a, short8 b, f32x16 c) {
  return __builtin_amdgcn_mfma_f32_32x32x16_bf16(a, b, c, 0, 0, 0);
}

// ---------------------------------------------------------------------------
// prep: bf16 weight images (fragment-major, conflict-free) + starts[]
// (starts[s] = first i with batch[i] >= s; batch is sorted).
// ---------------------------------------------------------------------------
__global__ void prep_all(const float* __restrict__ w1, const float* __restrict__ w2,
                         const float* __restrict__ w3, const int* __restrict__ batch,
                         unsigned short* __restrict__ w1p, uint4* __restrict__ wimg,
                         int* __restrict__ starts, int N, int B) {
  const int i = blockIdx.x * 256 + threadIdx.x;
  if (i == 0) {
    const int b0 = batch[0];
    for (int s = 0; s <= b0; ++s) starts[s] = 0;
    const int bl = batch[N - 1];
    for (int s = bl + 1; s <= B; ++s) starts[s] = N;
  } else if (i < N) {
    const int a = batch[i - 1], b = batch[i];
    for (int s = a + 1; s <= b; ++s) starts[s] = i;
  }
  if (i < 512) {
    { int c = i >> 4, k = i & 15; w1p[i] = (k < 6) ? f2bf(w1[c * 6 + k]) : (unsigned short)0; }
    const int l31 = i & 31, rest = i >> 5;
    const int g = rest & 1, n = (rest >> 1) & 1, t2 = rest >> 2;
    const float* src = w2 + (l31 + 32 * t2) * 32 + n * 16 + 8 * g;
    uint4 v;
    v.x = (unsigned)f2bf(src[0]) | ((unsigned)f2bf(src[1]) << 16);
    v.y = (unsigned)f2bf(src[2]) | ((unsigned)f2bf(src[3]) << 16);
    v.z = (unsigned)f2bf(src[4]) | ((unsigned)f2bf(src[5]) << 16);
    v.w = (unsigned)f2bf(src[6]) | ((unsigned)f2bf(src[7]) << 16);
    wimg[i] = v;
  }
  if (i < 4096) {
    const int l31 = i & 31, rest = i >> 5;
    const int g = rest & 1, k0 = (rest >> 1) & 7, t = rest >> 4;
    const float* src = w3 + (l31 + 32 * t) * 128 + k0 * 16 + 8 * g;
    uint4 v;
    v.x = (unsigned)f2bf(src[0]) | ((unsigned)f2bf(src[1]) << 16);
    v.y = (unsigned)f2bf(src[2]) | ((unsigned)f2bf(src[3]) << 16);
    v.z = (unsigned)f2bf(src[4]) | ((unsigned)f2bf(src[5]) << 16);
    v.w = (unsigned)f2bf(src[6]) | ((unsigned)f2bf(src[7]) << 16);
    wimg[512 + i] = v;
  }
}

// ---------------------------------------------------------------------------
// Fused per-point MLP (6->32->128->256, bf16 MFMA) + segment-max.
// SEGMENT-OWNED WAVES (R9): wave s processes exactly the points of
// segment s ([starts[s], starts[s+1])), accumulates the max in registers,
// and writes xmax row s with PLAIN coalesced stores. Every row has exactly
// one writer -> zero atomics, zero memset, zero merge machinery. (R4-R8
// showed duration invariant under atomic placement/timing: the ~2M
// device-scope lane-atomics themselves were the wall.)
// 8 waves/block; w2+w3 staged once per block in LDS (72KB, fragment-major).
// Activations stay in registers (cvt_pk + shfl_xor(32) transpose).
// Tail subtile (<32 valid points) masked via wave-uniform nv bound on the
// C/D index map idx=(r&3)+8*(r>>2)+4g.
// ---------------------------------------------------------------------------
__global__ __launch_bounds__(512, 4) void mlp_segmax_mfma(
    const float* __restrict__ points, const float* __restrict__ color,
    const int* __restrict__ starts,
    const unsigned short* __restrict__ w1p, const uint4* __restrict__ wimg,
    const float* __restrict__ b1, const float* __restrict__ b2, const float* __restrict__ b3,
    float* __restrict__ xmax, int N, int B)
{
  __shared__ __align__(16) uint4 smem[4608];   // 8KB w2 image + 64KB w3 image
  const int tid  = threadIdx.x;
  const int wv   = tid >> 6;
  const int lane = tid & 63;
  const int g    = lane >> 5;
  const int l31  = lane & 31;

  for (int i = tid; i < 4608; i += 512) smem[i] = wimg[i];
  __syncthreads();
  const char* w2c = (const char*)smem;
  const char* w3c = (const char*)(smem + 512);

  const short8 a1 = *reinterpret_cast<const short8*>(w1p + l31 * 16 + 8 * g);
  float b3v[8];
#pragma unroll
  for (int t = 0; t < 8; ++t) b3v[t] = b3[32 * t + l31];

  const int s = blockIdx.x * 8 + wv;          // segment owned by this wave
  if (s >= B) return;
  const int i0 = starts[s], i1 = starts[s + 1];

  float rmax[8];
#pragma unroll
  for (int t = 0; t < 8; ++t) rmax[t] = -INFINITY;

  // ---- input prefetch for first subtile ----
  float n0 = 0, n1 = 0, n2 = 0, n3 = 0, n4 = 0, n5 = 0;
  if (i0 < i1) {
    const int p = min(i0 + l31, N - 1);
    n0 = points[p * 3 + 0]; n1 = points[p * 3 + 1]; n2 = points[p * 3 + 2];
    n3 = color[p * 3 + 0];  n4 = color[p * 3 + 1];  n5 = color[p * 3 + 2];
  }

  for (int p0 = i0; p0 < i1; p0 += 32) {
    const float c0 = n0, c1 = n1, c2 = n2, c3 = n3, c4 = n4, c5 = n5;
    if (p0 + 32 < i1) {
      const int p = min(p0 + 32 + l31, N - 1);
      n0 = points[p * 3 + 0]; n1 = points[p * 3 + 1]; n2 = points[p * 3 + 2];
      n3 = color[p * 3 + 0];  n4 = color[p * 3 + 1];  n5 = color[p * 3 + 2];
    }
    const int nv = min(i1 - p0, 32);            // wave-uniform valid count

    // opaque per-iteration handles: keep bias loads + LDS reads inside the loop
    unsigned long long b1a = (unsigned long long)b1; asm volatile("" : "+s"(b1a));
    unsigned long long b2a = (unsigned long long)b2; asm volatile("" : "+s"(b2a));
    const float* b1l = (const float*)b1a;
    const float* b2l = (const float*)b2a;
    int z = 0; asm volatile("" : "+v"(z));      // opaque 0 for LDS offsets

    // ---------------- layer 1 (6->32): D[ch][pt] ----------------
    const unsigned int zm = (g == 0) ? 0xffffffffu : 0u;  // g=1 lanes = K-pad
    U8 bin;
    bin.u[0] = cvtpk(c0, c1) & zm;
    bin.u[1] = cvtpk(c2, c3) & zm;
    bin.u[2] = cvtpk(c4, c5) & zm;
    bin.u[3] = 0;
    f32x16 ci;
#pragma unroll
    for (int q2 = 0; q2 < 4; ++q2) {
      const float4 bv = *reinterpret_cast<const float4*>(b1l + 8 * q2 + 4 * g);
      ci[4 * q2 + 0] = bv.x; ci[4 * q2 + 1] = bv.y; ci[4 * q2 + 2] = bv.z; ci[4 * q2 + 3] = bv.w;
    }
    f32x16 d1 = MFMA(a1, bin.s, ci);

    unsigned int W1[4][2];
#pragma unroll
    for (int q2 = 0; q2 < 4; ++q2) {
      W1[q2][0] = pkrelu(d1[4 * q2 + 0], d1[4 * q2 + 1]);
      W1[q2][1] = pkrelu(d1[4 * q2 + 2], d1[4 * q2 + 3]);
    }
    U8 h1f[2];
#pragma unroll
    for (int n = 0; n < 2; ++n) {
      unsigned int r0 = __shfl_xor(W1[2 * n + 1 - g][0], 32);
      unsigned int r1 = __shfl_xor(W1[2 * n + 1 - g][1], 32);
      h1f[n].u[0] = (g == 0) ? W1[2 * n + g][0] : r0;
      h1f[n].u[1] = (g == 0) ? W1[2 * n + g][1] : r1;
      h1f[n].u[2] = (g == 1) ? W1[2 * n + g][0] : r0;
      h1f[n].u[3] = (g == 1) ? W1[2 * n + g][1] : r1;
    }

    // ---------------- layer 2 (32->128): D[ch][pt] per 32-ch tile ----------------
    unsigned int own2[4][2][2], rc2[4][2][2];
#pragma unroll
    for (int t2 = 0; t2 < 4; ++t2) {
      f32x16 cc;
#pragma unroll
      for (int q2 = 0; q2 < 4; ++q2) {
        const float4 bv = *reinterpret_cast<const float4*>(b2l + 32 * t2 + 8 * q2 + 4 * g);
        cc[4 * q2 + 0] = bv.x; cc[4 * q2 + 1] = bv.y; cc[4 * q2 + 2] = bv.z; cc[4 * q2 + 3] = bv.w;
      }
      const short8 a20 = *reinterpret_cast<const short8*>(
          w2c + ((((t2 * 2 + 0) * 2 + g) * 32 + l31) << 4) + z);
      const short8 a21 = *reinterpret_cast<const short8*>(
          w2c + ((((t2 * 2 + 1) * 2 + g) * 32 + l31) << 4) + z);
      f32x16 d2 = MFMA(a20, h1f[0].s, cc);
      d2 = MFMA(a21, h1f[1].s, d2);
      unsigned int Wt[4][2];
#pragma unroll
      for (int q2 = 0; q2 < 4; ++q2) {
        Wt[q2][0] = pkrelu(d2[4 * q2 + 0], d2[4 * q2 + 1]);
        Wt[q2][1] = pkrelu(d2[4 * q2 + 2], d2[4 * q2 + 3]);
      }
#pragma unroll
      for (int m = 0; m < 2; ++m) {
        own2[t2][m][0] = Wt[2 * m + g][0];
        own2[t2][m][1] = Wt[2 * m + g][1];
        rc2[t2][m][0] = __shfl_xor(Wt[2 * m + 1 - g][0], 32);
        rc2[t2][m][1] = __shfl_xor(Wt[2 * m + 1 - g][1], 32);
      }
    }
    U8 a3[8];
#pragma unroll
    for (int k0 = 0; k0 < 8; ++k0) {
      const int t2 = k0 >> 1, m = k0 & 1;
      a3[k0].u[0] = (g == 0) ? own2[t2][m][0] : rc2[t2][m][0];
      a3[k0].u[1] = (g == 0) ? own2[t2][m][1] : rc2[t2][m][1];
      a3[k0].u[2] = (g == 1) ? own2[t2][m][0] : rc2[t2][m][0];
      a3[k0].u[3] = (g == 1) ? own2[t2][m][1] : rc2[t2][m][1];
    }

    // ---------------- layer 3 (128->256): D[pt][ch], col=channel ----------------
    if (nv == 32) {           // full subtile (wave-uniform branch)
#pragma unroll
      for (int t = 0; t < 8; ++t) {
        f32x16 acc;
#pragma unroll
        for (int r2 = 0; r2 < 16; ++r2) acc[r2] = b3v[t];
#pragma unroll
        for (int k0 = 0; k0 < 8; ++k0) {
          const short8 bf = *reinterpret_cast<const short8*>(
              w3c + ((((t * 8 + k0) * 2 + g) * 32 + l31) << 4) + z);
          acc = MFMA(a3[k0].s, bf, acc);
        }
        float m = acc[0];
#pragma unroll
        for (int r2 = 1; r2 < 16; ++r2) m = fmaxf(m, acc[r2]);
        rmax[t] = fmaxf(rmax[t], m);
      }
    } else {                  // tail subtile: mask points with idx >= nv
#pragma unroll
      for (int t = 0; t < 8; ++t) {
        f32x16 acc;
#pragma unroll
        for (int r2 = 0; r2 < 16; ++r2) acc[r2] = b3v[t];
#pragma unroll
        for (int k0 = 0; k0 < 8; ++k0) {
          const short8 bf = *reinterpret_cast<const short8*>(
              w3c + ((((t * 8 + k0) * 2 + g) * 32 + l31) << 4) + z);
          acc = MFMA(a3[k0].s, bf, acc);
        }
        float m = -INFINITY;
#pragma unroll
        for (int r2 = 0; r2 < 16; ++r2) {
          const int idx = (r2 & 3) + 8 * (r2 >> 2) + 4 * g;
          m = fmaxf(m, (idx < nv) ? acc[r2] : -INFINITY);
        }
        rmax[t] = fmaxf(rmax[t], m);
      }
    }
  }

  // ---- sole writer of row s: plain coalesced stores, clamp at 0 ----
#pragma unroll
  for (int t = 0; t < 8; ++t) {
    float v = fmaxf(rmax[t], __shfl_xor(rmax[t], 32));
    if (lane < 32) xmax[(long long)s * 256 + 32 * t + lane] = fmaxf(v, 0.0f);
  }
}

// ---------------------------------------------------------------------------
// FC head  [B,256] -> 128 -> 64 -> 75, + coef scale/shift
// ---------------------------------------------------------------------------
__global__ __launch_bounds__(256) void head_kernel(
    const float* __restrict__ xmax,
    const float* __restrict__ fw1, const float* __restrict__ fb1,
    const float* __restrict__ fw2, const float* __restrict__ fb2,
    const float* __restrict__ fw3, const float* __restrict__ fb3,
    const float* __restrict__ cmean, const float* __restrict__ cstd,
    float* __restrict__ out, int B)
{
  __shared__ __align__(16) float xm[16][260];
  __shared__ __align__(16) float h1b[16][132];
  __shared__ __align__(16) float h2b[16][68];

  const int t = threadIdx.x;
  const int bbase = blockIdx.x * 16;

  for (int i = t; i < 16 * 256; i += 256) {
    const int bi = i >> 8, k = i & 255;
    const int bb = min(bbase + bi, B - 1);
    xm[bi][k] = xmax[(long long)bb * 256 + k];
  }
  __syncthreads();

  {
    const int bi = t >> 4, oi = t & 15;
    float acc[8];
#pragma unroll
    for (int u = 0; u < 8; ++u) acc[u] = fb1[oi * 8 + u];
    for (int k = 0; k < 256; k += 4) {
      const float4 xv = *reinterpret_cast<const float4*>(&xm[bi][k]);
#pragma unroll
      for (int u = 0; u < 8; ++u) {
        const float4 wv = *reinterpret_cast<const float4*>(fw1 + (oi * 8 + u) * 256 + k);
        acc[u] = fmaf(xv.x, wv.x, acc[u]);
        acc[u] = fmaf(xv.y, wv.y, acc[u]);
        acc[u] = fmaf(xv.z, wv.z, acc[u]);
        acc[u] = fmaf(xv.w, wv.w, acc[u]);
      }
    }
#pragma unroll
    for (int u = 0; u < 8; ++u) h1b[bi][oi * 8 + u] = fmaxf(acc[u], 0.0f);
  }
  __syncthreads();

  {
    const int bi = t >> 4, oi = t & 15;
    float acc[4];
#pragma unroll
    for (int u = 0; u < 4; ++u) acc[u] = fb2[oi * 4 + u];
    for (int k = 0; k < 128; k += 4) {
      const float4 xv = *reinterpret_cast<const float4*>(&h1b[bi][k]);
#pragma unroll
      for (int u = 0; u < 4; ++u) {
        const float4 wv = *reinterpret_cast<const float4*>(fw2 + (oi * 4 + u) * 128 + k);
        acc[u] = fmaf(xv.x, wv.x, acc[u]);
        acc[u] = fmaf(xv.y, wv.y, acc[u]);
        acc[u] = fmaf(xv.z, wv.z, acc[u]);
        acc[u] = fmaf(xv.w, wv.w, acc[u]);
      }
    }
#pragma unroll
    for (int u = 0; u < 4; ++u) h2b[bi][oi * 4 + u] = fmaxf(acc[u], 0.0f);
  }
  __syncthreads();

  for (int i = t; i < 16 * 75; i += 256) {
    const int bi = i / 75, o = i - bi * 75;
    float a = fb3[o];
    for (int k = 0; k < 64; k += 4) {
      const float4 xv = *reinterpret_cast<const float4*>(&h2b[bi][k]);
      const float4 wv = *reinterpret_cast<const float4*>(fw3 + o * 64 + k);
      a = fmaf(xv.x, wv.x, a);
      a = fmaf(xv.y, wv.y, a);
      a = fmaf(xv.z, wv.z, a);
      a = fmaf(xv.w, wv.w, a);
    }
    const int b = bbase + bi;
    if (b < B) out[(long long)b * 75 + o] = fmaf(a, cstd[o], cmean[o]);
  }
}

extern "C" void kernel_launch(void* const* d_in, const int* in_sizes, int n_in,
                              void* d_out, int out_size, void* d_ws, size_t ws_size,
                              hipStream_t stream) {
  const float* points = (const float*)d_in[0];
  const float* color  = (const float*)d_in[1];
  const int*   batch  = (const int*)d_in[2];
  const float* w1  = (const float*)d_in[3];
  const float* b1  = (const float*)d_in[4];
  const float* w2  = (const float*)d_in[5];
  const float* b2  = (const float*)d_in[6];
  const float* w3  = (const float*)d_in[7];
  const float* b3  = (const float*)d_in[8];
  const float* fw1 = (const float*)d_in[9];
  const float* fb1 = (const float*)d_in[10];
  const float* fw2 = (const float*)d_in[11];
  const float* fb2 = (const float*)d_in[12];
  const float* fw3 = (const float*)d_in[13];
  const float* fb3 = (const float*)d_in[14];
  const float* cmean = (const float*)d_in[15];
  const float* cstd  = (const float*)d_in[16];
  float* out = (float*)d_out;

  const int N = in_sizes[2];
  const int B = out_size / 75;

  // workspace: xmax 4MB | w1p 1KB | wimg 72KB | starts (B+1)*4
  char* ws = (char*)d_ws;
  float* xmax = (float*)ws;
  unsigned short* w1p = (unsigned short*)(ws + 4194304);
  uint4* wimg = (uint4*)(ws + 4198400);
  int* starts = (int*)(ws + 4198400 + 4608 * 16);

  prep_all<<<(N + 255) / 256, 256, 0, stream>>>(w1, w2, w3, batch,
                                                w1p, wimg, starts, N, B);

  const int nBlocks = (B + 7) / 8;   // one wave per segment
  mlp_segmax_mfma<<<nBlocks, 512, 0, stream>>>(points, color, starts,
                                               w1p, wimg, b1, b2, b3,
                                               xmax, N, B);

  head_kernel<<<(B + 15) / 16, 256, 0, stream>>>(xmax, fw1, fb1, fw2, fb2, fw3, fb3,
                                                 cmean, cstd, out, B);
}